// Round 13
// baseline (270.285 us; speedup 1.0000x reference)
//
#include <hip/hip_runtime.h>
#include <stdint.h>

typedef unsigned short u16;
typedef __attribute__((ext_vector_type(8))) __bf16 bf16x8;
typedef __attribute__((ext_vector_type(4))) float f32x4;
typedef __attribute__((ext_vector_type(4))) unsigned short u16x4;

__device__ __forceinline__ float bf2f(u16 u){
  unsigned int x = ((unsigned int)u) << 16;
  return __builtin_bit_cast(float, x);
}
__device__ __forceinline__ u16 f2bf(float f){
  unsigned int u = __builtin_bit_cast(unsigned int, f);
  u += 0x7fffu + ((u >> 16) & 1u);   // RNE
  return (u16)(u >> 16);
}
__device__ __forceinline__ float fexp2(float x){ return __builtin_exp2f(x); }
// global -> LDS direct DMA, 16B/lane. LDS dest = wave-uniform base (+lane*16).
__device__ __forceinline__ void lds_load16(const void* g, void* l){
  __builtin_amdgcn_global_load_lds(
      (const __attribute__((address_space(1))) unsigned int*)g,
      (__attribute__((address_space(3))) unsigned int*)l, 16, 0, 0);
}

// ------- transpose+convert: out_bf16[C][R] = in_f32[R][C], 64x64 tiles -------
__global__ __launch_bounds__(256) void transpose64(const float* __restrict__ in,
                                                   u16* __restrict__ out,
                                                   int R, int C){
  __shared__ u16 t[64][65];
  const int c0 = blockIdx.x * 64, r0 = blockIdx.y * 64;
  const int tid = threadIdx.x;
  const int rr = tid >> 3;          // 0..31
  const int cc = (tid & 7) * 8;     // 0..56
#pragma unroll
  for (int i = 0; i < 2; i++){
    int r = i * 32 + rr;
    const float* p = in + (size_t)(r0 + r) * C + c0 + cc;
    f32x4 v0 = *(const f32x4*)p;
    f32x4 v1 = *(const f32x4*)(p + 4);
#pragma unroll
    for (int j = 0; j < 4; j++){ t[r][cc + j] = f2bf(v0[j]); t[r][cc + 4 + j] = f2bf(v1[j]); }
  }
  __syncthreads();
#pragma unroll
  for (int i = 0; i < 2; i++){
    int c = i * 32 + rr;
    u16 tmp[8];
#pragma unroll
    for (int j = 0; j < 8; j++) tmp[j] = t[cc + j][c];
    *(bf16x8*)(out + (size_t)(c0 + c) * R + r0 + cc) = *(const bf16x8*)tmp;
  }
}

// ------- x (f32) -> bf16 flat convert ----------------------------------------
__global__ __launch_bounds__(256) void convert_bf16(const float* __restrict__ in,
                                                    u16* __restrict__ out){
  int t = blockIdx.x * 256 + threadIdx.x;
  const float* p = in + (size_t)t * 8;
  f32x4 v0 = *(const f32x4*)p;
  f32x4 v1 = *(const f32x4*)(p + 4);
  u16 tmp[8];
#pragma unroll
  for (int j = 0; j < 4; j++){ tmp[j] = f2bf(v0[j]); tmp[4 + j] = f2bf(v1[j]); }
  *(bf16x8*)(out + (size_t)t * 8) = *(const bf16x8*)tmp;
}

// ------- vT[bh][d=64][s=2048] = V third of qkv, per-head transposed ----------
__global__ __launch_bounds__(256) void v_transpose(const u16* __restrict__ qkv,
                                                   u16* __restrict__ vT){
  const int S = 2048, LD = 3072;
  __shared__ u16 t[64][65];
  const int bh = blockIdx.y;
  const int b = bh >> 4, h = bh & 15;
  const int s0 = blockIdx.x * 64;
  const u16* src = qkv + (size_t)b * S * LD + 2048 + h * 64;
  const int tid = threadIdx.x;
  const int rr = tid >> 3;
  const int cc = (tid & 7) * 8;
#pragma unroll
  for (int i = 0; i < 2; i++){
    int s = i * 32 + rr;
    bf16x8 v = *(const bf16x8*)(src + (size_t)(s0 + s) * LD + cc);
#pragma unroll
    for (int j = 0; j < 8; j++) t[s][cc + j] = __builtin_bit_cast(u16, (__bf16)v[j]);
  }
  __syncthreads();
  u16* dst = vT + (size_t)bh * 64 * S;
#pragma unroll
  for (int i = 0; i < 2; i++){
    int d = i * 32 + rr;
    u16 tmp[8];
#pragma unroll
    for (int j = 0; j < 8; j++) tmp[j] = t[cc + j][d];
    *(bf16x8*)(dst + (size_t)d * S + s0 + cc) = *(const bf16x8*)tmp;
  }
}

// -------- GEMM (all-bf16, m97 DMA staging + XCD swizzle) ---------------------
// ROPE: fuse RoPE into epilogue for q/k columns (bn<16, wave-uniform).
template<bool OUTF32, bool ROPE>
__global__ __launch_bounds__(256, 2) void gemm_bt(const u16* __restrict__ A,
                                                  const u16* __restrict__ Bt,
                                                  const float* __restrict__ bias,
                                                  void* __restrict__ Cv,
                                                  int M, int N, int K,
                                                  const float* __restrict__ cosb,
                                                  const float* __restrict__ sinb){
  __shared__ u16 As[128 * 32];
  __shared__ u16 Bs[128 * 32];
  // bijective XCD chunking (nwg % 8 == 0 for both call sites)
  const int nx = gridDim.x;
  const int L = blockIdx.x + nx * blockIdx.y;
  const int per = (nx * gridDim.y) >> 3;
  const int wg = (L & 7) * per + (L >> 3);
  const int bn = wg % nx, bm = wg / nx;
  const int tid = threadIdx.x, w = tid >> 6, l = tid & 63;
  const int lo = l & 15, hi = l >> 4;
  const int wr = (w >> 1) * 64, wc = (w & 1) * 64;
  f32x4 acc[4][4] = {};
  const int lrow = l >> 2, lcd = l & 3;   // lane -> row-in-16, chunk

  for (int k0 = 0; k0 < K; k0 += 32){
#pragma unroll
    for (int i = 0; i < 2; i++){
      int row0 = i * 64 + w * 16;
      int row = row0 + lrow;
      int cs = lcd ^ ((row >> 1) & 3);    // pre-swizzled source chunk
      lds_load16(A  + (size_t)(bm * 128 + row) * K + k0 + cs * 8,
                 (char*)As + row0 * 64);
      lds_load16(Bt + (size_t)(bn * 128 + row) * K + k0 + cs * 8,
                 (char*)Bs + row0 * 64);
    }
    __syncthreads();
    bf16x8 a[4], b[4];
#pragma unroll
    for (int mi = 0; mi < 4; mi++){
      int row = wr + mi * 16 + lo;
      unsigned byte = (unsigned)(row * 64 + hi * 16) ^ (((row >> 1) & 3) << 4);
      a[mi] = *(const bf16x8*)((const char*)As + byte);
    }
#pragma unroll
    for (int ni = 0; ni < 4; ni++){
      int row = wc + ni * 16 + lo;
      unsigned byte = (unsigned)(row * 64 + hi * 16) ^ (((row >> 1) & 3) << 4);
      b[ni] = *(const bf16x8*)((const char*)Bs + byte);
    }
    __builtin_amdgcn_s_setprio(1);
#pragma unroll
    for (int mi = 0; mi < 4; mi++)
#pragma unroll
      for (int ni = 0; ni < 4; ni++)
        acc[mi][ni] = __builtin_amdgcn_mfma_f32_16x16x32_bf16(a[mi], b[ni], acc[mi][ni], 0, 0, 0);
    __builtin_amdgcn_s_setprio(0);
    __syncthreads();
  }
  if (ROPE && bn < 16){
    // q/k epilogue: val = acc + bias, then rope pair (even,odd col) via shfl
#pragma unroll
    for (int mi = 0; mi < 4; mi++){
#pragma unroll
      for (int r = 0; r < 4; r++){
        int grow = bm * 128 + wr + mi * 16 + hi * 4 + r;
        int stok = grow & 2047;
#pragma unroll
        for (int ni = 0; ni < 4; ni++){
          int col = bn * 128 + wc + ni * 16 + lo;
          float v = acc[mi][ni][r] + bias[col];
          float partner = __shfl_xor(v, 1, 64);
          int ip = (col & 63) >> 1;
          float c = cosb[stok * 32 + ip], sn = sinb[stok * 32 + ip];
          float res = (lo & 1) ? (partner * sn + v * c) : (v * c - partner * sn);
          ((u16*)Cv)[(size_t)grow * N + col] = f2bf(res);
        }
      }
    }
  } else {
#pragma unroll
    for (int mi = 0; mi < 4; mi++){
#pragma unroll
      for (int r = 0; r < 4; r++){
        int grow = bm * 128 + wr + mi * 16 + hi * 4 + r;
#pragma unroll
        for (int ni = 0; ni < 4; ni++){
          int col = bn * 128 + wc + ni * 16 + lo;
          float v = acc[mi][ni][r] + bias[col];
          if (OUTF32)
            ((float*)Cv)[(size_t)grow * N + col] = v;
          else
            ((u16*)Cv)[(size_t)grow * N + col] = f2bf(v);
        }
      }
    }
  }
}

// ---- flash attention: 1-wave blocks, reg-dbuf K prefetch, XCD-local ---------
// Grid 4096: bh = L & 31 (32%8==0 -> head pinned to one XCD, K/V L2-local),
// T = 127 - (L>>5) heavy-first. K prefetched 1 tile ahead into named register
// buffers kA/kB via TEXTUAL macros (no array-by-ref: avoids r6 scratch trap).
// vmcnt discipline: kA loads oldest -> QK wait leaves kB+V in flight.
// Only LDS: P roundtrip (2.3 KB).
#define FA_LOADK(KB_, KT_)                                                     \
  { _Pragma("unroll")                                                          \
    for (int c = 0; c < 2; c++){                                               \
      _Pragma("unroll")                                                        \
      for (int f = 0; f < 4; f++)                                              \
        KB_[c * 4 + f] = *(const bf16x8*)(Kp +                                 \
            (size_t)((KT_) * 64 + f * 16 + lo) * LD + c * 32 + hi * 8);        \
    } }

#define FA_BODY(KB_, KT_)                                                      \
  {                                                                            \
    bf16x8 vb[8];                                                              \
    _Pragma("unroll")                                                          \
    for (int c = 0; c < 2; c++){                                               \
      _Pragma("unroll")                                                        \
      for (int fd = 0; fd < 4; fd++)                                           \
        vb[c * 4 + fd] = *(const bf16x8*)(Vb +                                 \
            (size_t)(fd * 16 + lo) * S + (KT_) * 64 + c * 32 + hi * 8);        \
    }                                                                          \
    f32x4 sa[4] = {};                                                          \
    __builtin_amdgcn_s_setprio(1);                                             \
    _Pragma("unroll")                                                          \
    for (int c = 0; c < 2; c++){                                               \
      _Pragma("unroll")                                                        \
      for (int f = 0; f < 4; f++)                                              \
        sa[f] = __builtin_amdgcn_mfma_f32_16x16x32_bf16(KB_[c * 4 + f],        \
                                                        qf[c], sa[f], 0, 0, 0);\
    }                                                                          \
    __builtin_amdgcn_s_setprio(0);                                             \
    if ((KT_) == nkt - 1){                                                     \
      _Pragma("unroll")                                                        \
      for (int f = 0; f < 4; f++){                                             \
        int key0 = (KT_) * 64 + f * 16 + hi * 4;                               \
        _Pragma("unroll")                                                      \
        for (int r = 0; r < 4; r++)                                            \
          if (key0 + r > qrow) sa[f][r] = -1e30f;                              \
      }                                                                        \
    }                                                                          \
    float pmax = sa[0][0];                                                     \
    _Pragma("unroll")                                                          \
    for (int f = 0; f < 4; f++){                                               \
      _Pragma("unroll")                                                        \
      for (int r = 0; r < 4; r++) pmax = fmaxf(pmax, sa[f][r]);                \
    }                                                                          \
    if (!__all(pmax - m_r <= 11.5f)){                                          \
      float rowmax = fmaxf(pmax, __shfl_xor(pmax, 16, 64));                    \
      rowmax = fmaxf(rowmax, __shfl_xor(rowmax, 32, 64));                      \
      float mnew = fmaxf(m_r, rowmax);                                         \
      float corr = fexp2(m_r - mnew);                                          \
      m_r = mnew;                                                              \
      l_par *= corr;                                                           \
      float corr_q[4];                                                         \
      _Pragma("unroll")                                                        \
      for (int r = 0; r < 4; r++) corr_q[r] = __shfl(corr, hi * 4 + r, 64);    \
      _Pragma("unroll")                                                        \
      for (int fd = 0; fd < 4; fd++){                                          \
        _Pragma("unroll")                                                      \
        for (int r = 0; r < 4; r++) o[fd][r] *= corr_q[r];                     \
      }                                                                        \
    }                                                                          \
    float psum = 0.f;                                                          \
    _Pragma("unroll")                                                          \
    for (int f = 0; f < 4; f++){                                               \
      u16x4 pk;                                                                \
      _Pragma("unroll")                                                        \
      for (int r = 0; r < 4; r++){                                             \
        float pv = fexp2(sa[f][r] - m_r);                                      \
        psum += pv;                                                            \
        pk[r] = f2bf(pv);                                                      \
      }                                                                        \
      *(u16x4*)((char*)Ps + lo * 144 + f * 32 + hi * 8) = pk;                  \
    }                                                                          \
    l_par += psum;                                                             \
    bf16x8 pa[2];                                                              \
    _Pragma("unroll")                                                          \
    for (int c = 0; c < 2; c++)                                                \
      pa[c] = *(const bf16x8*)((const char*)Ps + lo * 144 + c * 64 + hi * 16); \
    __builtin_amdgcn_s_setprio(1);                                             \
    _Pragma("unroll")                                                          \
    for (int fd = 0; fd < 4; fd++){                                            \
      _Pragma("unroll")                                                        \
      for (int c = 0; c < 2; c++)                                              \
        o[fd] = __builtin_amdgcn_mfma_f32_16x16x32_bf16(pa[c], vb[c * 4 + fd], \
                                                        o[fd], 0, 0, 0);       \
    }                                                                          \
    __builtin_amdgcn_s_setprio(0);                                             \
  }

__global__ __launch_bounds__(64, 4) void flash_attn(const u16* __restrict__ qkv,
                                                    const u16* __restrict__ vT,
                                                    u16* __restrict__ Oout){
  const int S = 2048, LD = 3072;
  const int L = blockIdx.x;
  const int bh = L & 31;
  const int T = 127 - (L >> 5);
  const int b = bh >> 4, h = bh & 15;
  const u16* base = qkv + (size_t)b * S * LD;
  const u16* Qp = base + h * 64;
  const u16* Kp = base + 1024 + h * 64;
  const u16* Vb = vT + (size_t)bh * 64 * S;
  const int l = threadIdx.x & 63;
  const int lo = l & 15, hi = l >> 4;
  __shared__ u16 Ps[16 * 72];               // P roundtrip, 144B row stride

  const float QSC = 0.125f * 1.44269504089f;  // -> log2 domain
  const int q0 = T * 16;
  const int qrow = q0 + lo;
  const int nkt = (T >> 2) + 1;

  bf16x8 qf[2];
#pragma unroll
  for (int c = 0; c < 2; c++){
    bf16x8 qv = *(const bf16x8*)(Qp + (size_t)qrow * LD + c * 32 + hi * 8);
#pragma unroll
    for (int j = 0; j < 8; j++) qf[c][j] = (__bf16)((float)qv[j] * QSC);
  }

  f32x4 o[4] = {};
  float m_r = -1e30f, l_par = 0.f;

  bf16x8 kA[8], kB[8];
  FA_LOADK(kA, 0);
  int kt = 0;
  while (true){
    if (kt + 1 < nkt) FA_LOADK(kB, kt + 1);
    FA_BODY(kA, kt);
    kt++;
    if (kt >= nkt) break;
    if (kt + 1 < nkt) FA_LOADK(kA, kt + 1);
    FA_BODY(kB, kt);
    kt++;
    if (kt >= nkt) break;
  }
  // ---- final l reduce + normalize + store ----
  float lsum = l_par;
  lsum += __shfl_xor(lsum, 16, 64);
  lsum += __shfl_xor(lsum, 32, 64);
  float linv = 1.0f / lsum;
  float inv_q[4];
#pragma unroll
  for (int r = 0; r < 4; r++) inv_q[r] = __shfl(linv, hi * 4 + r, 64);
#pragma unroll
  for (int r = 0; r < 4; r++){
    int srow = q0 + hi * 4 + r;
    u16* orow = Oout + (size_t)(b * S + srow) * 1024 + h * 64;
#pragma unroll
    for (int fd = 0; fd < 4; fd++)
      orow[fd * 16 + lo] = f2bf(o[fd][r] * inv_q[r]);
  }
}

extern "C" void kernel_launch(void* const* d_in, const int* in_sizes, int n_in,
                              void* d_out, int out_size, void* d_ws, size_t ws_size,
                              hipStream_t stream){
  const float* x     = (const float*)d_in[0];
  const float* w_qkv = (const float*)d_in[1];
  const float* b_qkv = (const float*)d_in[2];
  const float* w_out = (const float*)d_in[3];
  const float* b_out = (const float*)d_in[4];
  const float* cosb  = (const float*)d_in[5];
  const float* sinb  = (const float*)d_in[6];
  // d_in[7] = mask: causal, implemented analytically.
  float* out = (float*)d_out;
  char* ws = (char*)d_ws;
  u16* qkv  = (u16*)(ws);               // bf16 [4096][3072]   25.2 MB
  u16* attn = (u16*)(ws + 25165824);    // bf16 [4096][1024]    8.4 MB
  u16* xbf  = attn;                     // x bf16 — dead before flash writes attn
  u16* wT2  = (u16*)(ws + 33554432);    // w_out^T bf16 [1024][1024]  2.1 MB
  u16* wT1  = (u16*)(ws + 35651584);    // w_qkv^T bf16 [3072][1024]  6.3 MB
  u16* vT   = (u16*)(ws + 35651584);    // vT — overlaps wT1 (dead after GEMM1)

  transpose64<<<dim3(48, 16), 256, 0, stream>>>(w_qkv, wT1, 1024, 3072);
  transpose64<<<dim3(16, 16), 256, 0, stream>>>(w_out, wT2, 1024, 1024);
  convert_bf16<<<2048, 256, 0, stream>>>(x, xbf);
  gemm_bt<false, true ><<<dim3(24, 32), 256, 0, stream>>>(xbf, wT1, b_qkv, qkv,
                                                          4096, 3072, 1024, cosb, sinb);
  v_transpose<<<dim3(32, 32), 256, 0, stream>>>(qkv, vT);
  flash_attn<<<4096, 64, 0, stream>>>(qkv, vT, attn);
  gemm_bt<true , false><<<dim3(8, 32), 256, 0, stream>>>(attn, wT2, b_out, out,
                                                         4096, 1024, 1024, cosb, sinb);
}

// Round 14
// 160.339 us; speedup vs baseline: 1.6857x; 1.6857x over previous
//
#include <hip/hip_runtime.h>
#include <stdint.h>

typedef unsigned short u16;
typedef __attribute__((ext_vector_type(8))) __bf16 bf16x8;
typedef __attribute__((ext_vector_type(4))) float f32x4;
typedef __attribute__((ext_vector_type(4))) unsigned short u16x4;

__device__ __forceinline__ float bf2f(u16 u){
  unsigned int x = ((unsigned int)u) << 16;
  return __builtin_bit_cast(float, x);
}
__device__ __forceinline__ u16 f2bf(float f){
  unsigned int u = __builtin_bit_cast(unsigned int, f);
  u += 0x7fffu + ((u >> 16) & 1u);   // RNE
  return (u16)(u >> 16);
}
__device__ __forceinline__ float fexp2(float x){ return __builtin_exp2f(x); }
// global -> LDS direct DMA, 16B/lane. LDS dest = wave-uniform base (+lane*16).
__device__ __forceinline__ void lds_load16(const void* g, void* l){
  __builtin_amdgcn_global_load_lds(
      (const __attribute__((address_space(1))) unsigned int*)g,
      (__attribute__((address_space(3))) unsigned int*)l, 16, 0, 0);
}

// ------- transpose+convert: out_bf16[C][R] = in_f32[R][C], 64x64 tiles -------
__global__ __launch_bounds__(256) void transpose64(const float* __restrict__ in,
                                                   u16* __restrict__ out,
                                                   int R, int C){
  __shared__ u16 t[64][65];
  const int c0 = blockIdx.x * 64, r0 = blockIdx.y * 64;
  const int tid = threadIdx.x;
  const int rr = tid >> 3;          // 0..31
  const int cc = (tid & 7) * 8;     // 0..56
#pragma unroll
  for (int i = 0; i < 2; i++){
    int r = i * 32 + rr;
    const float* p = in + (size_t)(r0 + r) * C + c0 + cc;
    f32x4 v0 = *(const f32x4*)p;
    f32x4 v1 = *(const f32x4*)(p + 4);
#pragma unroll
    for (int j = 0; j < 4; j++){ t[r][cc + j] = f2bf(v0[j]); t[r][cc + 4 + j] = f2bf(v1[j]); }
  }
  __syncthreads();
#pragma unroll
  for (int i = 0; i < 2; i++){
    int c = i * 32 + rr;
    u16 tmp[8];
#pragma unroll
    for (int j = 0; j < 8; j++) tmp[j] = t[cc + j][c];
    *(bf16x8*)(out + (size_t)(c0 + c) * R + r0 + cc) = *(const bf16x8*)tmp;
  }
}

// ------- x (f32) -> bf16 flat convert ----------------------------------------
__global__ __launch_bounds__(256) void convert_bf16(const float* __restrict__ in,
                                                    u16* __restrict__ out){
  int t = blockIdx.x * 256 + threadIdx.x;
  const float* p = in + (size_t)t * 8;
  f32x4 v0 = *(const f32x4*)p;
  f32x4 v1 = *(const f32x4*)(p + 4);
  u16 tmp[8];
#pragma unroll
  for (int j = 0; j < 4; j++){ tmp[j] = f2bf(v0[j]); tmp[4 + j] = f2bf(v1[j]); }
  *(bf16x8*)(out + (size_t)t * 8) = *(const bf16x8*)tmp;
}

// ------- vT[bh][d=64][s=2048] = V third of qkv, per-head transposed ----------
__global__ __launch_bounds__(256) void v_transpose(const u16* __restrict__ qkv,
                                                   u16* __restrict__ vT){
  const int S = 2048, LD = 3072;
  __shared__ u16 t[64][65];
  const int bh = blockIdx.y;
  const int b = bh >> 4, h = bh & 15;
  const int s0 = blockIdx.x * 64;
  const u16* src = qkv + (size_t)b * S * LD + 2048 + h * 64;
  const int tid = threadIdx.x;
  const int rr = tid >> 3;
  const int cc = (tid & 7) * 8;
#pragma unroll
  for (int i = 0; i < 2; i++){
    int s = i * 32 + rr;
    bf16x8 v = *(const bf16x8*)(src + (size_t)(s0 + s) * LD + cc);
#pragma unroll
    for (int j = 0; j < 8; j++) t[s][cc + j] = __builtin_bit_cast(u16, (__bf16)v[j]);
  }
  __syncthreads();
  u16* dst = vT + (size_t)bh * 64 * S;
#pragma unroll
  for (int i = 0; i < 2; i++){
    int d = i * 32 + rr;
    u16 tmp[8];
#pragma unroll
    for (int j = 0; j < 8; j++) tmp[j] = t[cc + j][d];
    *(bf16x8*)(dst + (size_t)d * S + s0 + cc) = *(const bf16x8*)tmp;
  }
}

// -------- GEMM (all-bf16, m97 DMA staging + XCD swizzle) ---------------------
// ROPE: fuse RoPE into epilogue for q/k columns (bn<16, wave-uniform).
template<bool OUTF32, bool ROPE>
__global__ __launch_bounds__(256, 2) void gemm_bt(const u16* __restrict__ A,
                                                  const u16* __restrict__ Bt,
                                                  const float* __restrict__ bias,
                                                  void* __restrict__ Cv,
                                                  int M, int N, int K,
                                                  const float* __restrict__ cosb,
                                                  const float* __restrict__ sinb){
  __shared__ u16 As[128 * 32];
  __shared__ u16 Bs[128 * 32];
  // bijective XCD chunking (nwg % 8 == 0 for both call sites)
  const int nx = gridDim.x;
  const int L = blockIdx.x + nx * blockIdx.y;
  const int per = (nx * gridDim.y) >> 3;
  const int wg = (L & 7) * per + (L >> 3);
  const int bn = wg % nx, bm = wg / nx;
  const int tid = threadIdx.x, w = tid >> 6, l = tid & 63;
  const int lo = l & 15, hi = l >> 4;
  const int wr = (w >> 1) * 64, wc = (w & 1) * 64;
  f32x4 acc[4][4] = {};
  const int lrow = l >> 2, lcd = l & 3;   // lane -> row-in-16, chunk

  for (int k0 = 0; k0 < K; k0 += 32){
#pragma unroll
    for (int i = 0; i < 2; i++){
      int row0 = i * 64 + w * 16;
      int row = row0 + lrow;
      int cs = lcd ^ ((row >> 1) & 3);    // pre-swizzled source chunk
      lds_load16(A  + (size_t)(bm * 128 + row) * K + k0 + cs * 8,
                 (char*)As + row0 * 64);
      lds_load16(Bt + (size_t)(bn * 128 + row) * K + k0 + cs * 8,
                 (char*)Bs + row0 * 64);
    }
    __syncthreads();
    bf16x8 a[4], b[4];
#pragma unroll
    for (int mi = 0; mi < 4; mi++){
      int row = wr + mi * 16 + lo;
      unsigned byte = (unsigned)(row * 64 + hi * 16) ^ (((row >> 1) & 3) << 4);
      a[mi] = *(const bf16x8*)((const char*)As + byte);
    }
#pragma unroll
    for (int ni = 0; ni < 4; ni++){
      int row = wc + ni * 16 + lo;
      unsigned byte = (unsigned)(row * 64 + hi * 16) ^ (((row >> 1) & 3) << 4);
      b[ni] = *(const bf16x8*)((const char*)Bs + byte);
    }
    __builtin_amdgcn_s_setprio(1);
#pragma unroll
    for (int mi = 0; mi < 4; mi++)
#pragma unroll
      for (int ni = 0; ni < 4; ni++)
        acc[mi][ni] = __builtin_amdgcn_mfma_f32_16x16x32_bf16(a[mi], b[ni], acc[mi][ni], 0, 0, 0);
    __builtin_amdgcn_s_setprio(0);
    __syncthreads();
  }
  if (ROPE && bn < 16){
    // q/k epilogue: val = acc + bias, then rope pair (even,odd col) via shfl
#pragma unroll
    for (int mi = 0; mi < 4; mi++){
#pragma unroll
      for (int r = 0; r < 4; r++){
        int grow = bm * 128 + wr + mi * 16 + hi * 4 + r;
        int stok = grow & 2047;
#pragma unroll
        for (int ni = 0; ni < 4; ni++){
          int col = bn * 128 + wc + ni * 16 + lo;
          float v = acc[mi][ni][r] + bias[col];
          float partner = __shfl_xor(v, 1, 64);
          int ip = (col & 63) >> 1;
          float c = cosb[stok * 32 + ip], sn = sinb[stok * 32 + ip];
          float res = (lo & 1) ? (partner * sn + v * c) : (v * c - partner * sn);
          ((u16*)Cv)[(size_t)grow * N + col] = f2bf(res);
        }
      }
    }
  } else {
#pragma unroll
    for (int mi = 0; mi < 4; mi++){
#pragma unroll
      for (int r = 0; r < 4; r++){
        int grow = bm * 128 + wr + mi * 16 + hi * 4 + r;
#pragma unroll
        for (int ni = 0; ni < 4; ni++){
          int col = bn * 128 + wc + ni * 16 + lo;
          float v = acc[mi][ni][r] + bias[col];
          if (OUTF32)
            ((float*)Cv)[(size_t)grow * N + col] = v;
          else
            ((u16*)Cv)[(size_t)grow * N + col] = f2bf(v);
        }
      }
    }
  }
}

// ---- flash attention (r11 structure): 1-wave blocks, LDS-DMA K dbuf,
// XCD-local heads, zero barriers, exact work balance --------------------------
// Grid 2048: bh = L & 31 (32%8==0 -> head pinned to one XCD, K/V L2-local),
// bx = L >> 5; block handles q-tiles {127-bx, bx} -> exactly 33 K-iterations.
// Wave-private LDS K double-buffer via global_load_lds (no VGPR cost for
// staged data); P roundtrip. No __syncthreads; compiler vmcnt/lgkmcnt orders.
__global__ __launch_bounds__(64, 2) void flash_attn(const u16* __restrict__ qkv,
                                                    const u16* __restrict__ vT,
                                                    u16* __restrict__ Oout){
  const int S = 2048, LD = 3072;
  const int L = blockIdx.x;
  const int bh = L & 31;
  const int bx = L >> 5;
  const int b = bh >> 4, h = bh & 15;
  const u16* base = qkv + (size_t)b * S * LD;
  const u16* Qp = base + h * 64;
  const u16* Kp = base + 1024 + h * 64;
  const u16* Vb = vT + (size_t)bh * 64 * S;
  const int l = threadIdx.x & 63;
  const int lo = l & 15, hi = l >> 4;
  __shared__ u16 Ks[2][64 * 64];            // wave-private (1-wave block)
  __shared__ u16 Ps[16 * 72];               // P roundtrip, 144B row stride

  const float QSC = 0.125f * 1.44269504089f;  // -> log2 domain
  const int srow8 = l >> 3;
  const int scs = (l & 7) ^ srow8;          // DMA source chunk (row&7==l>>3)

  const int tiles0 = 127 - bx;              // heavy tile first
  const int tiles1 = bx;

#pragma unroll 1
  for (int tsel = 0; tsel < 2; tsel++){
    const int T = tsel ? tiles1 : tiles0;
    const int q0 = T * 16;
    const int qrow = q0 + lo;
    const int nkt = ((q0 + 15) >> 6) + 1;

    bf16x8 qf[2];
#pragma unroll
    for (int c = 0; c < 2; c++){
      bf16x8 qv = *(const bf16x8*)(Qp + (size_t)qrow * LD + c * 32 + hi * 8);
#pragma unroll
      for (int j = 0; j < 8; j++) qf[c][j] = (__bf16)((float)qv[j] * QSC);
    }

    f32x4 o[4] = {};
    float m_r = -1e30f, l_par = 0.f;

    // prologue: stage K tile 0 into buf 0 (8 x 1KB issues)
#pragma unroll
    for (int i = 0; i < 8; i++)
      lds_load16(Kp + (size_t)(i * 8 + srow8) * LD + scs * 8,
                 (char*)&Ks[0][0] + i * 1024);

    int cur = 0;
    for (int kt = 0; kt < nkt; kt++){
      // ---- V^T B-frags issued first (fly during lgkm wait on K ds_reads) ----
      bf16x8 vb[2][4];
#pragma unroll
      for (int c = 0; c < 2; c++)
#pragma unroll
        for (int fd = 0; fd < 4; fd++)
          vb[c][fd] = *(const bf16x8*)(Vb + (size_t)(fd * 16 + lo) * S + kt * 64 + c * 32 + hi * 8);
      // ---- K frags from Ks[cur] (vmcnt wait covers only older DMA) ----
      bf16x8 kb[2][4];
#pragma unroll
      for (int c = 0; c < 2; c++)
#pragma unroll
        for (int f = 0; f < 4; f++){
          int srow = f * 16 + lo;
          unsigned byte = ((unsigned)(srow * 128 + c * 64 + hi * 16)) ^ ((srow & 7) << 4);
          kb[c][f] = *(const bf16x8*)((const char*)&Ks[cur][0] + byte);
        }
      // ---- issue next K stage (prefetch, drains next iteration) ----
      if (kt + 1 < nkt){
#pragma unroll
        for (int i = 0; i < 8; i++)
          lds_load16(Kp + (size_t)((kt + 1) * 64 + i * 8 + srow8) * LD + scs * 8,
                     (char*)&Ks[cur ^ 1][0] + i * 1024);
      }
      // ---- S^T = K * Q^T (log2 domain) ----
      f32x4 sa[4] = {};
      __builtin_amdgcn_s_setprio(1);
#pragma unroll
      for (int c = 0; c < 2; c++)
#pragma unroll
        for (int f = 0; f < 4; f++)
          sa[f] = __builtin_amdgcn_mfma_f32_16x16x32_bf16(kb[c][f], qf[c], sa[f], 0, 0, 0);
      __builtin_amdgcn_s_setprio(0);
      // ---- causal mask: only the last K-tile can cross the diagonal ----
      if (kt == nkt - 1){
#pragma unroll
        for (int f = 0; f < 4; f++){
          int key0 = kt * 64 + f * 16 + hi * 4;
#pragma unroll
          for (int r = 0; r < 4; r++)
            if (key0 + r > qrow) sa[f][r] = -1e30f;
        }
      }
      // ---- defer-max online softmax (common path: no cross-lane ops) ----
      float pmax = sa[0][0];
#pragma unroll
      for (int f = 0; f < 4; f++)
#pragma unroll
        for (int r = 0; r < 4; r++) pmax = fmaxf(pmax, sa[f][r]);
      if (!__all(pmax - m_r <= 11.5f)){
        float rowmax = fmaxf(pmax, __shfl_xor(pmax, 16, 64));
        rowmax = fmaxf(rowmax, __shfl_xor(rowmax, 32, 64));
        float mnew = fmaxf(m_r, rowmax);
        float corr = fexp2(m_r - mnew);
        m_r = mnew;
        l_par *= corr;
        float corr_q[4];
#pragma unroll
        for (int r = 0; r < 4; r++) corr_q[r] = __shfl(corr, hi * 4 + r, 64);
#pragma unroll
        for (int fd = 0; fd < 4; fd++)
#pragma unroll
          for (int r = 0; r < 4; r++) o[fd][r] *= corr_q[r];
      }
      float psum = 0.f;
      float p[4][4];
#pragma unroll
      for (int f = 0; f < 4; f++)
#pragma unroll
        for (int r = 0; r < 4; r++){
          float pv = fexp2(sa[f][r] - m_r);
          p[f][r] = pv;
          psum += pv;
        }
      l_par += psum;
      // ---- P[q=lo][k] -> LDS (packed 8B), read back as A-frags ----
#pragma unroll
      for (int f = 0; f < 4; f++){
        u16x4 pk;
#pragma unroll
        for (int r = 0; r < 4; r++) pk[r] = f2bf(p[f][r]);
        *(u16x4*)((char*)Ps + lo * 144 + f * 32 + hi * 8) = pk;
      }
      bf16x8 pa[2];
#pragma unroll
      for (int c = 0; c < 2; c++)
        pa[c] = *(const bf16x8*)((const char*)Ps + lo * 144 + c * 64 + hi * 16);
      // ---- O += P V ----
      __builtin_amdgcn_s_setprio(1);
#pragma unroll
      for (int fd = 0; fd < 4; fd++)
#pragma unroll
        for (int c = 0; c < 2; c++)
          o[fd] = __builtin_amdgcn_mfma_f32_16x16x32_bf16(pa[c], vb[c][fd], o[fd], 0, 0, 0);
      __builtin_amdgcn_s_setprio(0);
      cur ^= 1;
    }
    // ---- final l reduce + normalize + store ----
    float lsum = l_par;
    lsum += __shfl_xor(lsum, 16, 64);
    lsum += __shfl_xor(lsum, 32, 64);
    float linv = 1.0f / lsum;
    float inv_q[4];
#pragma unroll
    for (int r = 0; r < 4; r++) inv_q[r] = __shfl(linv, hi * 4 + r, 64);
#pragma unroll
    for (int r = 0; r < 4; r++){
      int srow = q0 + hi * 4 + r;
      u16* orow = Oout + (size_t)(b * S + srow) * 1024 + h * 64;
#pragma unroll
      for (int fd = 0; fd < 4; fd++)
        orow[fd * 16 + lo] = f2bf(o[fd][r] * inv_q[r]);
    }
  }
}

extern "C" void kernel_launch(void* const* d_in, const int* in_sizes, int n_in,
                              void* d_out, int out_size, void* d_ws, size_t ws_size,
                              hipStream_t stream){
  const float* x     = (const float*)d_in[0];
  const float* w_qkv = (const float*)d_in[1];
  const float* b_qkv = (const float*)d_in[2];
  const float* w_out = (const float*)d_in[3];
  const float* b_out = (const float*)d_in[4];
  const float* cosb  = (const float*)d_in[5];
  const float* sinb  = (const float*)d_in[6];
  // d_in[7] = mask: causal, implemented analytically.
  float* out = (float*)d_out;
  char* ws = (char*)d_ws;
  u16* qkv  = (u16*)(ws);               // bf16 [4096][3072]   25.2 MB
  u16* attn = (u16*)(ws + 25165824);    // bf16 [4096][1024]    8.4 MB
  u16* xbf  = attn;                     // x bf16 — dead before flash writes attn
  u16* wT2  = (u16*)(ws + 33554432);    // w_out^T bf16 [1024][1024]  2.1 MB
  u16* wT1  = (u16*)(ws + 35651584);    // w_qkv^T bf16 [3072][1024]  6.3 MB
  u16* vT   = (u16*)(ws + 35651584);    // vT — overlaps wT1 (dead after GEMM1)

  transpose64<<<dim3(48, 16), 256, 0, stream>>>(w_qkv, wT1, 1024, 3072);
  transpose64<<<dim3(16, 16), 256, 0, stream>>>(w_out, wT2, 1024, 1024);
  convert_bf16<<<2048, 256, 0, stream>>>(x, xbf);
  gemm_bt<false, true ><<<dim3(24, 32), 256, 0, stream>>>(xbf, wT1, b_qkv, qkv,
                                                          4096, 3072, 1024, cosb, sinb);
  v_transpose<<<dim3(32, 32), 256, 0, stream>>>(qkv, vT);
  flash_attn<<<2048, 64, 0, stream>>>(qkv, vT, attn);
  gemm_bt<true , false><<<dim3(8, 32), 256, 0, stream>>>(attn, wT2, b_out, out,
                                                         4096, 1024, 1024, cosb, sinb);
}

// Round 15
// 157.497 us; speedup vs baseline: 1.7161x; 1.0180x over previous
//
#include <hip/hip_runtime.h>
#include <stdint.h>

typedef unsigned short u16;
typedef __attribute__((ext_vector_type(8))) __bf16 bf16x8;
typedef __attribute__((ext_vector_type(4))) float f32x4;
typedef __attribute__((ext_vector_type(4))) unsigned short u16x4;

__device__ __forceinline__ float bf2f(u16 u){
  unsigned int x = ((unsigned int)u) << 16;
  return __builtin_bit_cast(float, x);
}
__device__ __forceinline__ u16 f2bf(float f){
  unsigned int u = __builtin_bit_cast(unsigned int, f);
  u += 0x7fffu + ((u >> 16) & 1u);   // RNE
  return (u16)(u >> 16);
}
__device__ __forceinline__ float fexp2(float x){ return __builtin_exp2f(x); }
// global -> LDS direct DMA, 16B/lane. LDS dest = wave-uniform base (+lane*16).
__device__ __forceinline__ void lds_load16(const void* g, void* l){
  __builtin_amdgcn_global_load_lds(
      (const __attribute__((address_space(1))) unsigned int*)g,
      (__attribute__((address_space(3))) unsigned int*)l, 16, 0, 0);
}

// ------- transpose+convert: out_bf16[C][R] = in_f32[R][C], 64x64 tiles -------
__global__ __launch_bounds__(256) void transpose64(const float* __restrict__ in,
                                                   u16* __restrict__ out,
                                                   int R, int C){
  __shared__ u16 t[64][65];
  const int c0 = blockIdx.x * 64, r0 = blockIdx.y * 64;
  const int tid = threadIdx.x;
  const int rr = tid >> 3;          // 0..31
  const int cc = (tid & 7) * 8;     // 0..56
#pragma unroll
  for (int i = 0; i < 2; i++){
    int r = i * 32 + rr;
    const float* p = in + (size_t)(r0 + r) * C + c0 + cc;
    f32x4 v0 = *(const f32x4*)p;
    f32x4 v1 = *(const f32x4*)(p + 4);
#pragma unroll
    for (int j = 0; j < 4; j++){ t[r][cc + j] = f2bf(v0[j]); t[r][cc + 4 + j] = f2bf(v1[j]); }
  }
  __syncthreads();
#pragma unroll
  for (int i = 0; i < 2; i++){
    int c = i * 32 + rr;
    u16 tmp[8];
#pragma unroll
    for (int j = 0; j < 8; j++) tmp[j] = t[cc + j][c];
    *(bf16x8*)(out + (size_t)(c0 + c) * R + r0 + cc) = *(const bf16x8*)tmp;
  }
}

// ------- x (f32) -> bf16 flat convert ----------------------------------------
__global__ __launch_bounds__(256) void convert_bf16(const float* __restrict__ in,
                                                    u16* __restrict__ out){
  int t = blockIdx.x * 256 + threadIdx.x;
  const float* p = in + (size_t)t * 8;
  f32x4 v0 = *(const f32x4*)p;
  f32x4 v1 = *(const f32x4*)(p + 4);
  u16 tmp[8];
#pragma unroll
  for (int j = 0; j < 4; j++){ tmp[j] = f2bf(v0[j]); tmp[4 + j] = f2bf(v1[j]); }
  *(bf16x8*)(out + (size_t)t * 8) = *(const bf16x8*)tmp;
}

// ------- vT[bh][d=64][s=2048] = V third of qkv, per-head transposed ----------
__global__ __launch_bounds__(256) void v_transpose(const u16* __restrict__ qkv,
                                                   u16* __restrict__ vT){
  const int S = 2048, LD = 3072;
  __shared__ u16 t[64][65];
  const int bh = blockIdx.y;
  const int b = bh >> 4, h = bh & 15;
  const int s0 = blockIdx.x * 64;
  const u16* src = qkv + (size_t)b * S * LD + 2048 + h * 64;
  const int tid = threadIdx.x;
  const int rr = tid >> 3;
  const int cc = (tid & 7) * 8;
#pragma unroll
  for (int i = 0; i < 2; i++){
    int s = i * 32 + rr;
    bf16x8 v = *(const bf16x8*)(src + (size_t)(s0 + s) * LD + cc);
#pragma unroll
    for (int j = 0; j < 8; j++) t[s][cc + j] = __builtin_bit_cast(u16, (__bf16)v[j]);
  }
  __syncthreads();
  u16* dst = vT + (size_t)bh * 64 * S;
#pragma unroll
  for (int i = 0; i < 2; i++){
    int d = i * 32 + rr;
    u16 tmp[8];
#pragma unroll
    for (int j = 0; j < 8; j++) tmp[j] = t[cc + j][d];
    *(bf16x8*)(dst + (size_t)d * S + s0 + cc) = *(const bf16x8*)tmp;
  }
}

// -------- GEMM (all-bf16, m97 DMA staging + XCD swizzle) ---------------------
// ROPE: fuse RoPE into epilogue for q/k columns (bn<16, wave-uniform).
template<bool OUTF32, bool ROPE>
__global__ __launch_bounds__(256, 2) void gemm_bt(const u16* __restrict__ A,
                                                  const u16* __restrict__ Bt,
                                                  const float* __restrict__ bias,
                                                  void* __restrict__ Cv,
                                                  int M, int N, int K,
                                                  const float* __restrict__ cosb,
                                                  const float* __restrict__ sinb){
  __shared__ u16 As[128 * 32];
  __shared__ u16 Bs[128 * 32];
  // bijective XCD chunking (nwg % 8 == 0 for both call sites)
  const int nx = gridDim.x;
  const int L = blockIdx.x + nx * blockIdx.y;
  const int per = (nx * gridDim.y) >> 3;
  const int wg = (L & 7) * per + (L >> 3);
  const int bn = wg % nx, bm = wg / nx;
  const int tid = threadIdx.x, w = tid >> 6, l = tid & 63;
  const int lo = l & 15, hi = l >> 4;
  const int wr = (w >> 1) * 64, wc = (w & 1) * 64;
  f32x4 acc[4][4] = {};
  const int lrow = l >> 2, lcd = l & 3;   // lane -> row-in-16, chunk

  for (int k0 = 0; k0 < K; k0 += 32){
#pragma unroll
    for (int i = 0; i < 2; i++){
      int row0 = i * 64 + w * 16;
      int row = row0 + lrow;
      int cs = lcd ^ ((row >> 1) & 3);    // pre-swizzled source chunk
      lds_load16(A  + (size_t)(bm * 128 + row) * K + k0 + cs * 8,
                 (char*)As + row0 * 64);
      lds_load16(Bt + (size_t)(bn * 128 + row) * K + k0 + cs * 8,
                 (char*)Bs + row0 * 64);
    }
    __syncthreads();
    bf16x8 a[4], b[4];
#pragma unroll
    for (int mi = 0; mi < 4; mi++){
      int row = wr + mi * 16 + lo;
      unsigned byte = (unsigned)(row * 64 + hi * 16) ^ (((row >> 1) & 3) << 4);
      a[mi] = *(const bf16x8*)((const char*)As + byte);
    }
#pragma unroll
    for (int ni = 0; ni < 4; ni++){
      int row = wc + ni * 16 + lo;
      unsigned byte = (unsigned)(row * 64 + hi * 16) ^ (((row >> 1) & 3) << 4);
      b[ni] = *(const bf16x8*)((const char*)Bs + byte);
    }
    __builtin_amdgcn_s_setprio(1);
#pragma unroll
    for (int mi = 0; mi < 4; mi++)
#pragma unroll
      for (int ni = 0; ni < 4; ni++)
        acc[mi][ni] = __builtin_amdgcn_mfma_f32_16x16x32_bf16(a[mi], b[ni], acc[mi][ni], 0, 0, 0);
    __builtin_amdgcn_s_setprio(0);
    __syncthreads();
  }
  if (ROPE && bn < 16){
    // q/k epilogue: val = acc + bias, then rope pair (even,odd col) via shfl
#pragma unroll
    for (int mi = 0; mi < 4; mi++){
#pragma unroll
      for (int r = 0; r < 4; r++){
        int grow = bm * 128 + wr + mi * 16 + hi * 4 + r;
        int stok = grow & 2047;
#pragma unroll
        for (int ni = 0; ni < 4; ni++){
          int col = bn * 128 + wc + ni * 16 + lo;
          float v = acc[mi][ni][r] + bias[col];
          float partner = __shfl_xor(v, 1, 64);
          int ip = (col & 63) >> 1;
          float c = cosb[stok * 32 + ip], sn = sinb[stok * 32 + ip];
          float res = (lo & 1) ? (partner * sn + v * c) : (v * c - partner * sn);
          ((u16*)Cv)[(size_t)grow * N + col] = f2bf(res);
        }
      }
    }
  } else {
#pragma unroll
    for (int mi = 0; mi < 4; mi++){
#pragma unroll
      for (int r = 0; r < 4; r++){
        int grow = bm * 128 + wr + mi * 16 + hi * 4 + r;
#pragma unroll
        for (int ni = 0; ni < 4; ni++){
          int col = bn * 128 + wc + ni * 16 + lo;
          float v = acc[mi][ni][r] + bias[col];
          if (OUTF32)
            ((float*)Cv)[(size_t)grow * N + col] = v;
          else
            ((u16*)Cv)[(size_t)grow * N + col] = f2bf(v);
        }
      }
    }
  }
}

// ---- flash attention: 1-wave blocks, 32-key LDS-DMA K dbuf, 4 waves/SIMD ----
// Grid 2048: bh = L & 31 (32%8==0 -> head pinned to one XCD, K/V L2-local),
// bx = L >> 5; block handles q-tiles {127-bx, bx} -> exactly 65 32-key
// iterations (uniform). LDS 9.3 KB: Ks[2][32x64] dbuf + Ps (72B stride,
// conflict-free 18-word banks) -> 16 blocks/CU = 4 waves/SIMD.
// No __syncthreads; compiler vmcnt/lgkmcnt orders DMA->ds_read.
__global__ __launch_bounds__(64, 4) void flash_attn(const u16* __restrict__ qkv,
                                                    const u16* __restrict__ vT,
                                                    u16* __restrict__ Oout){
  const int S = 2048, LD = 3072;
  const int L = blockIdx.x;
  const int bh = L & 31;
  const int bx = L >> 5;
  const int b = bh >> 4, h = bh & 15;
  const u16* base = qkv + (size_t)b * S * LD;
  const u16* Qp = base + h * 64;
  const u16* Kp = base + 1024 + h * 64;
  const u16* Vb = vT + (size_t)bh * 64 * S;
  const int l = threadIdx.x & 63;
  const int lo = l & 15, hi = l >> 4;
  __shared__ u16 Ks[2][32 * 64];            // 32 keys x 64 d, double-buffered
  __shared__ u16 Ps[16 * 36];               // P roundtrip, 72B row stride

  const float QSC = 0.125f * 1.44269504089f;  // -> log2 domain
  const int srow8 = l >> 3;
  const int scs = (l & 7) ^ srow8;          // DMA source chunk (row&7==l>>3)

  const int tiles0 = 127 - bx;              // heavy tile first
  const int tiles1 = bx;

#pragma unroll 1
  for (int tsel = 0; tsel < 2; tsel++){
    const int T = tsel ? tiles1 : tiles0;
    const int q0 = T * 16;
    const int qrow = q0 + lo;
    const int nkt = (T >> 1) + 1;           // 32-key tiles

    bf16x8 qf[2];
#pragma unroll
    for (int c = 0; c < 2; c++){
      bf16x8 qv = *(const bf16x8*)(Qp + (size_t)qrow * LD + c * 32 + hi * 8);
#pragma unroll
      for (int j = 0; j < 8; j++) qf[c][j] = (__bf16)((float)qv[j] * QSC);
    }

    f32x4 o[4] = {};
    float m_r = -1e30f, l_par = 0.f;

    // prologue: stage K tile 0 into buf 0 (4 x 1KB issues)
#pragma unroll
    for (int i = 0; i < 4; i++)
      lds_load16(Kp + (size_t)(i * 8 + srow8) * LD + scs * 8,
                 (char*)&Ks[0][0] + i * 1024);

    int cur = 0;
    for (int kt = 0; kt < nkt; kt++){
      // ---- V^T B-frags issued first (fly during lgkm wait on K ds_reads) ----
      bf16x8 vb[4];
#pragma unroll
      for (int fd = 0; fd < 4; fd++)
        vb[fd] = *(const bf16x8*)(Vb + (size_t)(fd * 16 + lo) * S + kt * 32 + hi * 8);
      // ---- K frags from Ks[cur] (vmcnt wait covers only older DMA) ----
      bf16x8 kb[2][2];
#pragma unroll
      for (int c = 0; c < 2; c++)
#pragma unroll
        for (int f = 0; f < 2; f++){
          int srow = f * 16 + lo;
          unsigned byte = ((unsigned)(srow * 128 + c * 64 + hi * 16)) ^ ((lo & 7) << 4);
          kb[c][f] = *(const bf16x8*)((const char*)&Ks[cur][0] + byte);
        }
      // ---- issue next K stage (prefetch, drains next iteration) ----
      if (kt + 1 < nkt){
#pragma unroll
        for (int i = 0; i < 4; i++)
          lds_load16(Kp + (size_t)((kt + 1) * 32 + i * 8 + srow8) * LD + scs * 8,
                     (char*)&Ks[cur ^ 1][0] + i * 1024);
      }
      // ---- S^T = K * Q^T (log2 domain) ----
      f32x4 sa[2] = {};
      __builtin_amdgcn_s_setprio(1);
#pragma unroll
      for (int c = 0; c < 2; c++)
#pragma unroll
        for (int f = 0; f < 2; f++)
          sa[f] = __builtin_amdgcn_mfma_f32_16x16x32_bf16(kb[c][f], qf[c], sa[f], 0, 0, 0);
      __builtin_amdgcn_s_setprio(0);
      // ---- causal mask: only the last K-tile can cross the diagonal ----
      if (kt == nkt - 1){
#pragma unroll
        for (int f = 0; f < 2; f++){
          int key0 = kt * 32 + f * 16 + hi * 4;
#pragma unroll
          for (int r = 0; r < 4; r++)
            if (key0 + r > qrow) sa[f][r] = -1e30f;
        }
      }
      // ---- defer-max online softmax (common path: no cross-lane ops) ----
      float pmax = sa[0][0];
#pragma unroll
      for (int f = 0; f < 2; f++)
#pragma unroll
        for (int r = 0; r < 4; r++) pmax = fmaxf(pmax, sa[f][r]);
      if (!__all(pmax - m_r <= 11.5f)){
        float rowmax = fmaxf(pmax, __shfl_xor(pmax, 16, 64));
        rowmax = fmaxf(rowmax, __shfl_xor(rowmax, 32, 64));
        float mnew = fmaxf(m_r, rowmax);
        float corr = fexp2(m_r - mnew);
        m_r = mnew;
        l_par *= corr;
        float corr_q[4];
#pragma unroll
        for (int r = 0; r < 4; r++) corr_q[r] = __shfl(corr, hi * 4 + r, 64);
#pragma unroll
        for (int fd = 0; fd < 4; fd++)
#pragma unroll
          for (int r = 0; r < 4; r++) o[fd][r] *= corr_q[r];
      }
      float psum = 0.f;
#pragma unroll
      for (int f = 0; f < 2; f++){
        u16x4 pk;
#pragma unroll
        for (int r = 0; r < 4; r++){
          float pv = fexp2(sa[f][r] - m_r);
          psum += pv;
          pk[r] = f2bf(pv);
        }
        *(u16x4*)((char*)Ps + lo * 72 + f * 32 + hi * 8) = pk;
      }
      l_par += psum;
      // ---- P[q=lo][k] read back as A-frag (single bf16x8) ----
      bf16x8 pa = *(const bf16x8*)((const char*)Ps + lo * 72 + hi * 16);
      // ---- O += P V ----
      __builtin_amdgcn_s_setprio(1);
#pragma unroll
      for (int fd = 0; fd < 4; fd++)
        o[fd] = __builtin_amdgcn_mfma_f32_16x16x32_bf16(pa, vb[fd], o[fd], 0, 0, 0);
      __builtin_amdgcn_s_setprio(0);
      cur ^= 1;
    }
    // ---- final l reduce + normalize + store ----
    float lsum = l_par;
    lsum += __shfl_xor(lsum, 16, 64);
    lsum += __shfl_xor(lsum, 32, 64);
    float linv = 1.0f / lsum;
    float inv_q[4];
#pragma unroll
    for (int r = 0; r < 4; r++) inv_q[r] = __shfl(linv, hi * 4 + r, 64);
#pragma unroll
    for (int r = 0; r < 4; r++){
      int srow = q0 + hi * 4 + r;
      u16* orow = Oout + (size_t)(b * S + srow) * 1024 + h * 64;
#pragma unroll
      for (int fd = 0; fd < 4; fd++)
        orow[fd * 16 + lo] = f2bf(o[fd][r] * inv_q[r]);
    }
  }
}

extern "C" void kernel_launch(void* const* d_in, const int* in_sizes, int n_in,
                              void* d_out, int out_size, void* d_ws, size_t ws_size,
                              hipStream_t stream){
  const float* x     = (const float*)d_in[0];
  const float* w_qkv = (const float*)d_in[1];
  const float* b_qkv = (const float*)d_in[2];
  const float* w_out = (const float*)d_in[3];
  const float* b_out = (const float*)d_in[4];
  const float* cosb  = (const float*)d_in[5];
  const float* sinb  = (const float*)d_in[6];
  // d_in[7] = mask: causal, implemented analytically.
  float* out = (float*)d_out;
  char* ws = (char*)d_ws;
  u16* qkv  = (u16*)(ws);               // bf16 [4096][3072]   25.2 MB
  u16* attn = (u16*)(ws + 25165824);    // bf16 [4096][1024]    8.4 MB
  u16* xbf  = attn;                     // x bf16 — dead before flash writes attn
  u16* wT2  = (u16*)(ws + 33554432);    // w_out^T bf16 [1024][1024]  2.1 MB
  u16* wT1  = (u16*)(ws + 35651584);    // w_qkv^T bf16 [3072][1024]  6.3 MB
  u16* vT   = (u16*)(ws + 35651584);    // vT — overlaps wT1 (dead after GEMM1)

  transpose64<<<dim3(48, 16), 256, 0, stream>>>(w_qkv, wT1, 1024, 3072);
  transpose64<<<dim3(16, 16), 256, 0, stream>>>(w_out, wT2, 1024, 1024);
  convert_bf16<<<2048, 256, 0, stream>>>(x, xbf);
  gemm_bt<false, true ><<<dim3(24, 32), 256, 0, stream>>>(xbf, wT1, b_qkv, qkv,
                                                          4096, 3072, 1024, cosb, sinb);
  v_transpose<<<dim3(32, 32), 256, 0, stream>>>(qkv, vT);
  flash_attn<<<2048, 64, 0, stream>>>(qkv, vT, attn);
  gemm_bt<true , false><<<dim3(8, 32), 256, 0, stream>>>(attn, wT2, b_out, out,
                                                         4096, 1024, 1024, cosb, sinb);
}